// Round 10
// baseline (182.446 us; speedup 1.0000x reference)
//
#include <hip/hip_runtime.h>
#include <hip/hip_bf16.h>

// Problem constants
#define NB 512     // batch
#define NP 1152    // primary capsules
#define NC 10      // digit capsules
#define ND 16      // output capsule dim
#define NI 8       // input capsule dim

constexpr int K_B    = 2;                // b's per lane
constexpr int B_TILE = 4 * 4 * K_B;      // 32 b per block (4 waves x 4 bsub x K_B)
constexpr int P_TILE = 8;                // p's per block
constexpr int NBLK_B = NB / B_TILE;      // 16
constexpr int NBLK_P = NP / P_TILE;      // 144
constexpr int SVD = NB * NC * ND;        // 81920
constexpr int W_TILE_BYTES = P_TILE * NC * ND * NI * 4;   // 40960
constexpr int X_TILE_FLOATS = B_TILE * P_TILE * NI;       // 2048 floats = 8KB

constexpr float LOG2E = 1.4426950408889634f;

typedef float v2f __attribute__((ext_vector_type(2)));

// 16-lane all-reduce sum via DPP (quad_perm xor1, xor2; row_ror 4, 8).
// Pure VALU. Result broadcast to all 16 lanes of the row.
__device__ __forceinline__ float red16_dpp(float v) {
    int t;
    t = __builtin_amdgcn_update_dpp(0, __float_as_int(v), 0xB1, 0xF, 0xF, true); // xor1
    v += __int_as_float(t);
    t = __builtin_amdgcn_update_dpp(0, __float_as_int(v), 0x4E, 0xF, 0xF, true); // xor2
    v += __int_as_float(t);
    t = __builtin_amdgcn_update_dpp(0, __float_as_int(v), 0x124, 0xF, 0xF, true); // row_ror:4
    v += __int_as_float(t);
    t = __builtin_amdgcn_update_dpp(0, __float_as_int(v), 0x128, 0xF, 0xF, true); // row_ror:8
    v += __int_as_float(t);
    return v;
}

// One routing pass. R10: KILL THE ATOMICS (two-stage reduction).
// Evidence chain R3-R9: pass floor ~73us invariant under VALU x3, occupancy
// 20-33%, LDS traffic x0.5, XCD affinity. WRITE_SIZE == 11.8M x 4B == one
// HBM write-through PER atomicAdd, unchanged by R9's XCD swizzle -> atomics
// are op-COUNT-throughput-bound at the coherence point:
// 11.8M / (8 XCD x ~16 atomic channels) ~= 92K cy ~= 38us — the floor.
// R10: TS mode writes per-pblk partial slices with PLAIN stores (no
// serialization); a fused reduce+squash kernel sums the 144 slices.
// Runtime ws_size guard picks TS vs legacy-atomic path (host branch only).
// Grid swizzle (R9, kept): bblk = id%16 -> per-bblk XCD affinity, x L2-local.
// W LDS swizzle involution: S(A) = A ^ (bit7(A)<<4) ^ (bit8(A)<<5).
// x LDS swizzle (R4, verified): physical unit u holds logical (bl, w16^(bl&3))
//   -> read XOR (bsub<<4): bsub hits bank-quads {0,4,8,12}, conflict-free.
// Softmax slimming (R2, verified): log2(e) folded into vr, NO max-subtraction
// (|lg*log2e| <~ 50 << 127, exp2-safe), v_rcp_f32 for 1/sum.
// VGPR-cap law (confirmed 4x): bounds(_,N) -> cap 256/N; (256,2) -> 128 >>
// demand ~72 -> no spill; HW residency LDS-capped at 3 blocks/CU.
// PASS 0: coup = 0.1;  PASS 1: logits = u.v0;  PASS 2: logits = u.(v0+v1)
template<int PASS, bool TS>
__global__ __launch_bounds__(256, 2)
void caps_pass(const float* __restrict__ x,    // [NB, NP, NI]
               const float* __restrict__ w,    // [NP, NC, ND, NI]
               const float* __restrict__ v0,   // [NB, NC, ND]
               const float* __restrict__ v1,   // [NB, NC, ND]
               float* __restrict__ s_out)      // TS: partial[NBLK_P][NB,NC,ND]; else s[NB,NC,ND]
{
    __shared__ __align__(16) float w_lds[W_TILE_BYTES / 4];   // 40KB
    __shared__ __align__(16) float x_lds[X_TILE_FLOATS];      // 8KB, [b][pp][i] swizzled

    const int tid  = threadIdx.x;
    const int lane = tid & 63;
    const int wave = tid >> 6;           // 0..3
    const int d    = lane & 15;
    const int bsub = lane >> 4;          // 0..3
    // R9 swizzle: id = pblk*16 + bblk -> id%8 = bblk%8 -> per-bblk XCD affinity.
    const int bblk = blockIdx.x % NBLK_B;
    const int pblk = blockIdx.x / NBLK_B;
    const int p0   = pblk * P_TILE;

    // ---- stage W tile: each wave loads one 10KB quarter (16B/lane, linear dest) ----
    {
        const uint8_t* wsrc = (const uint8_t*)w + (size_t)pblk * W_TILE_BYTES;
        // source offset: S(lane*16) within the 1KB chunk (bits 7,8 of chunk bases are 0)
        const int lane_src = (lane << 4) ^ ((lane & 8) << 1) ^ ((lane & 16) << 1);
        #pragma unroll
        for (int j = 0; j < 10; ++j) {
            const int off = wave * 10240 + j * 1024;
            __builtin_amdgcn_global_load_lds(
                (const __attribute__((address_space(1))) void*)(wsrc + off + lane_src),
                (__attribute__((address_space(3))) void*)((uint8_t*)w_lds + off),
                16, 0, 0);
        }
    }

    // ---- stage x tile: 8KB, linear LDS dest, swizzled global source ----
    // 16B unit u (0..511): bl = u>>4 (0..31), w16 = u&15 (= pp*2+half).
    // Physical LDS unit u holds logical unit (bl, w16 ^ (bl&3)) [byte bits 4-5].
    // Source strips stay 256B-contiguous per b.
    {
        #pragma unroll
        for (int j = 0; j < 2; ++j) {
            const int u   = wave * 128 + j * 64 + lane;
            const int bl  = u >> 4;
            const int w16 = u & 15;
            const float* bbase = x + ((size_t)(bblk * B_TILE + bl) * NP + p0) * NI;
            const uint8_t* src = (const uint8_t*)bbase + ((w16 ^ (bl & 3)) * 16);
            __builtin_amdgcn_global_load_lds(
                (const __attribute__((address_space(1))) void*)src,
                (__attribute__((address_space(3))) void*)((uint8_t*)x_lds + (size_t)u * 16),
                16, 0, 0);
        }
    }

    int bidx[K_B];
    #pragma unroll
    for (int k = 0; k < K_B; ++k) bidx[k] = bblk * B_TILE + wave * 8 + k * 4 + bsub;

    // v (v0, or v0+v1 for pass 2), pre-scaled by log2(e) — loop-invariant over p
    float vr[K_B][NC];
    if (PASS >= 1) {
        #pragma unroll
        for (int k = 0; k < K_B; ++k)
            #pragma unroll
            for (int c = 0; c < NC; ++c) {
                float vv = v0[(bidx[k] * NC + c) * ND + d];
                if (PASS == 2) vv += v1[(bidx[k] * NC + c) * ND + d];
                vr[k][c] = vv * LOG2E;
            }
    }

    float sacc[K_B][NC];
    #pragma unroll
    for (int k = 0; k < K_B; ++k)
        #pragma unroll
        for (int c = 0; c < NC; ++c) sacc[k][c] = 0.0f;

    // swizzled read offset for W[pp,c,d,0:4]: A = d*32 -> A ^ (bit2(d)<<4) ^ (bit3(d)<<5).
    // Half 2 at A+16 = lane_rd^16 (bit4 flip, bits 7,8 unchanged).
    const int lane_rd = (d << 5) ^ ((d & 4) << 2) ^ ((d & 8) << 2);
    const int xswz    = bsub << 4;   // x read swizzle (byte bits 4-5 ^= b&3)

    asm volatile("s_waitcnt vmcnt(0)" ::: "memory");   // W + x staging complete
    __syncthreads();                                   // all quarters visible to all waves

    for (int pp = 0; pp < P_TILE; ++pp) {
        v2f xv[K_B][4];
        #pragma unroll
        for (int k = 0; k < K_B; ++k) {
            const int xb = ((wave * 8 + k * 4 + bsub) * 256 + pp * 32) ^ xswz;
            const uint8_t* xp = (const uint8_t*)x_lds;
            const float4 a = *(const float4*)(xp + xb);
            const float4 b = *(const float4*)(xp + (xb ^ 16));
            xv[k][0] = v2f{a.x, a.y};
            xv[k][1] = v2f{a.z, a.w};
            xv[k][2] = v2f{b.x, b.y};
            xv[k][3] = v2f{b.z, b.w};
        }

        float uh[K_B][NC];
        #pragma unroll
        for (int c = 0; c < NC; ++c) {
            const uint8_t* pb = (const uint8_t*)w_lds + pp * 5120 + c * 512;
            const float4 wa = *(const float4*)(pb + lane_rd);          // W[p,c,d,0:4]
            const float4 wb = *(const float4*)(pb + (lane_rd ^ 16));   // W[p,c,d,4:8]
            const v2f w01{wa.x, wa.y}, w23{wa.z, wa.w};
            const v2f w45{wb.x, wb.y}, w67{wb.z, wb.w};
            #pragma unroll
            for (int k = 0; k < K_B; ++k) {
                v2f acc = w01 * xv[k][0];                              // v_pk_mul_f32
                acc = __builtin_elementwise_fma(w23, xv[k][1], acc);   // v_pk_fma_f32
                acc = __builtin_elementwise_fma(w45, xv[k][2], acc);
                acc = __builtin_elementwise_fma(w67, xv[k][3], acc);
                const float u = acc[0] + acc[1];
                if (PASS == 0) sacc[k][c] = fmaf(0.1f, u, sacc[k][c]);
                else           uh[k][c] = u;
            }
        }

        if (PASS >= 1) {
            #pragma unroll
            for (int k = 0; k < K_B; ++k) {
                float lg[NC];
                #pragma unroll
                for (int c = 0; c < NC; ++c)
                    lg[c] = red16_dpp(uh[k][c] * vr[k][c]);   // log2-domain logits
                float ssum = 0.0f;
                float coup[NC];
                #pragma unroll
                for (int c = 0; c < NC; ++c) {
                    coup[c] = __builtin_amdgcn_exp2f(lg[c]);  // no max-sub: bounded
                    ssum += coup[c];
                }
                const float inv = __builtin_amdgcn_rcpf(ssum);
                #pragma unroll
                for (int c = 0; c < NC; ++c)
                    sacc[k][c] = fmaf(coup[c] * inv, uh[k][c], sacc[k][c]);
            }
        }
    }

    // tail: each thread owns distinct (b,d). TS: plain stores into this
    // pblk's private slice (fire-and-forget, no serialization).
    // Legacy: device atomics (fallback when workspace too small).
    if (TS) {
        float* pout = s_out + (size_t)pblk * SVD;
        #pragma unroll
        for (int k = 0; k < K_B; ++k)
            #pragma unroll
            for (int c = 0; c < NC; ++c)
                pout[(bidx[k] * NC + c) * ND + d] = sacc[k][c];
    } else {
        #pragma unroll
        for (int k = 0; k < K_B; ++k)
            #pragma unroll
            for (int c = 0; c < NC; ++c)
                atomicAdd(&s_out[(bidx[k] * NC + c) * ND + d], sacc[k][c]);
    }
}

// R10: fused reduce (sum over the 144 pblk slices) + squash.
// 8 independent accumulator chains for memory ILP; reads are coalesced per
// slice (adjacent threads -> adjacent addresses). 46MB, mostly L3-resident
// (just written). Then squash: norm over d == 16-lane rows (idx&15 == lane&15).
__global__ __launch_bounds__(256)
void caps_reduce_squash(const float* __restrict__ part, float* __restrict__ v)
{
    const int idx = blockIdx.x * 256 + threadIdx.x;
    float a0 = 0, a1 = 0, a2 = 0, a3 = 0, a4 = 0, a5 = 0, a6 = 0, a7 = 0;
    #pragma unroll
    for (int r = 0; r < NBLK_P; r += 8) {
        a0 += part[(size_t)(r + 0) * SVD + idx];
        a1 += part[(size_t)(r + 1) * SVD + idx];
        a2 += part[(size_t)(r + 2) * SVD + idx];
        a3 += part[(size_t)(r + 3) * SVD + idx];
        a4 += part[(size_t)(r + 4) * SVD + idx];
        a5 += part[(size_t)(r + 5) * SVD + idx];
        a6 += part[(size_t)(r + 6) * SVD + idx];
        a7 += part[(size_t)(r + 7) * SVD + idx];
    }
    const float sv = ((a0 + a1) + (a2 + a3)) + ((a4 + a5) + (a6 + a7));
    float sq = red16_dpp(sv * sv);
    const float scale = (sq / (1.0f + sq)) / sqrtf(sq + 1e-7f);
    v[idx] = scale * sv;
}

// Legacy squash (fallback path). ZERO_S re-zeros s for the next pass.
template<bool ZERO_S>
__global__ __launch_bounds__(256)
void caps_squash(float* __restrict__ s, float* __restrict__ v)
{
    const int idx = blockIdx.x * 256 + threadIdx.x;
    const float sv = s[idx];
    if (ZERO_S) s[idx] = 0.0f;
    float sq = red16_dpp(sv * sv);
    const float scale = (sq / (1.0f + sq)) / sqrtf(sq + 1e-7f);
    v[idx] = scale * sv;
}

extern "C" void kernel_launch(void* const* d_in, const int* in_sizes, int n_in,
                              void* d_out, int out_size, void* d_ws, size_t ws_size,
                              hipStream_t stream)
{
    const float* x = (const float*)d_in[0];
    const float* w = (const float*)d_in[1];
    float* out = (float*)d_out;

    const dim3 pgrid(NBLK_B * NBLK_P);   // 2304 blocks of 256
    const dim3 pblock(256);
    const dim3 qgrid(SVD / 256);         // 320
    const dim3 qblock(256);

    const size_t partBytes = (size_t)NBLK_P * SVD * sizeof(float);   // ~47.2MB

    if (ws_size >= partBytes + (size_t)SVD * sizeof(float)) {
        // ---- two-stage path: no atomics, no memset ----
        float* part = (float*)d_ws;                                  // [NBLK_P][SVD]
        float* v0   = (float*)((uint8_t*)d_ws + partBytes);          // [SVD]
        float* v1   = out;                                           // reuse output

        caps_pass<0, true><<<pgrid, pblock, 0, stream>>>(x, w, nullptr, nullptr, part);
        caps_reduce_squash<<<qgrid, qblock, 0, stream>>>(part, v0);
        caps_pass<1, true><<<pgrid, pblock, 0, stream>>>(x, w, v0, nullptr, part);
        caps_reduce_squash<<<qgrid, qblock, 0, stream>>>(part, v1);
        caps_pass<2, true><<<pgrid, pblock, 0, stream>>>(x, w, v0, v1, part);
        caps_reduce_squash<<<qgrid, qblock, 0, stream>>>(part, out);
    } else {
        // ---- fallback: R9 atomic path ----
        float* s  = (float*)d_ws;       // [NB,NC,ND]
        float* v0 = s + SVD;            // [NB,NC,ND]
        float* v1 = out;

        hipMemsetAsync(s, 0, (size_t)SVD * sizeof(float), stream);
        caps_pass<0, false><<<pgrid, pblock, 0, stream>>>(x, w, nullptr, nullptr, s);
        caps_squash<true><<<qgrid, qblock, 0, stream>>>(s, v0);
        caps_pass<1, false><<<pgrid, pblock, 0, stream>>>(x, w, v0, nullptr, s);
        caps_squash<true><<<qgrid, qblock, 0, stream>>>(s, v1);
        caps_pass<2, false><<<pgrid, pblock, 0, stream>>>(x, w, v0, v1, s);
        caps_squash<false><<<qgrid, qblock, 0, stream>>>(s, out);
    }
}